// Round 8
// baseline (206.470 us; speedup 1.0000x reference)
//
#include <hip/hip_runtime.h>
#include <hip/hip_bf16.h>
#include <hip/hip_fp16.h>
#include <math.h>

// Problem: h = z @ W + b  (z [N,256] fp32, W [256,256] fp32, b [256])
//          out[e] = sigmoid(dot(h[src[e]], h[dst[e]]))  for E edges
// N = 100000, E = 300000, D = 256.
//
// R20: R19 (contiguous z loads, resident-B, swizzled A-tile: first real
// win, gemm ~62 -> ~49us) + the residual fix: per-strip __syncthreads
// drained vmcnt(0), force-waiting the next-strip loads a few hundred
// cycles after issue -> strip period = HBM latency (~2us x 24 strips
// ~= 49us, matches). Now: LDS-only barriers (s_waitcnt lgkmcnt(0) +
// s_barrier; global loads stay in flight, consumed via register
// data-dependency - NO cross-type vmcnt FIFO assumption, unlike racy
// R15), depth-2 strip prefetch in named reg buffers (body unrolled 2x,
// rule #20), and a block-wide swizzled epilogue tile so h-stores are
// perfectly linear (1KB contiguous per instruction; before: each store
// touched 16 rows 512B apart - same pathology as the fixed loads).

#define D_DIM 256
#define NBLK 256

typedef __attribute__((ext_vector_type(8))) _Float16 half8;
typedef __attribute__((ext_vector_type(4))) _Float16 half4;
typedef __attribute__((ext_vector_type(4))) float f32x4;

__device__ half8 g_Wf[8 * 256 * 4];   // [kb][fn][qd][fr], 128 KB

// 8192 threads: t -> (kb, qd, n), n fastest => coalesced row reads of W.
// frag(n = fn*16+fr, qd)[j] = W[(kb*32 + qd*8 + j)*256 + n]
__global__ __launch_bounds__(256) void pack_w_kernel(const float* __restrict__ W) {
  int t = blockIdx.x * 256 + threadIdx.x;   // 0..8191
  int kb = t >> 10;
  int qd = (t >> 8) & 3;
  int n  = t & 255;
  int fn = n >> 4;
  int fr = n & 15;
  half8 o;
#pragma unroll
  for (int j = 0; j < 8; j++)
    o[j] = (_Float16)W[(size_t)(kb * 32 + qd * 8 + j) * D_DIM + n];
  g_Wf[kb * 1024 + fn * 64 + qd * 16 + fr] = o;
}

// cvt two float4 (fp32 z data) and ds_write as fp16 into swizzled A-tile.
// Thread t covers strip rows t>>6 and (t>>6)+8. Swizzle: phys = row*512
// + (inner ^ ((row&7)<<4)).
__device__ inline void stage_write(char* tile, int tid, float4 A, float4 B) {
  int row = tid >> 6;                 // 0..7
  int inner = (tid & 63) * 8;         // byte offset in 512B fp16 row
  int sw = (row & 7) << 4;
  half4 p0, p1;
  p0[0] = (_Float16)A.x; p0[1] = (_Float16)A.y;
  p0[2] = (_Float16)A.z; p0[3] = (_Float16)A.w;
  p1[0] = (_Float16)B.x; p1[1] = (_Float16)B.y;
  p1[2] = (_Float16)B.z; p1[3] = (_Float16)B.w;
  *(half4*)(tile + row * 512 + (inner ^ sw)) = p0;
  *(half4*)(tile + (row + 8) * 512 + (inner ^ sw)) = p1;
}

// LDS-only barrier: drain LDS ops, keep global loads in flight.
#define SYNC_LDS() do {                                        \
    asm volatile("" ::: "memory");                             \
    asm volatile("s_waitcnt lgkmcnt(0)" ::: "memory");         \
    __builtin_amdgcn_s_barrier();                              \
    asm volatile("" ::: "memory");                             \
  } while (0)

// One strip: issue loads(S+2N) into LN regs; MFMA from AT; epilogue
// ds_write into AT (block-wide swizzled tile); stage A(S+N) from LC
// regs into AN; linear readback+store of strip S.
#define BODY(S, AT, AN, LC0, LC1, LN0, LN1) do {               \
    if ((S) + 2 * NBLK < nstrips) {                            \
      const char* sb = zb + (size_t)((S) + 2 * NBLK) * 16384;  \
      LN0 = *(const float4*)(sb + tid * 16);                   \
      LN1 = *(const float4*)(sb + 8192 + tid * 16);            \
    }                                                          \
    asm volatile("" ::: "memory");                             \
    f32x4 acc0 = (f32x4)0.f, acc1 = (f32x4)0.f;                \
    {                                                          \
      const char* abase = (AT) + fr * 512;                     \
      const int swz = (fr & 7) << 4;                           \
      _Pragma("unroll")                                        \
      for (int kb = 0; kb < 8; kb++) {                         \
        half8 af = *(const half8*)(abase + ((kb * 64 + qd * 16) ^ swz)); \
        half8 bf0 = bw[kb * 1024 + (2 * wv) * 64 + lane];      \
        half8 bf1 = bw[kb * 1024 + (2 * wv + 1) * 64 + lane];  \
        acc0 = __builtin_amdgcn_mfma_f32_16x16x32_f16(af, bf0, acc0, 0, 0, 0); \
        acc1 = __builtin_amdgcn_mfma_f32_16x16x32_f16(af, bf1, acc1, 0, 0, 0); \
      }                                                        \
    }                                                          \
    SYNC_LDS();   /* all waves done reading AT */              \
    {                                                          \
      char* tp = (char*)(AT);                                  \
      _Pragma("unroll")                                        \
      for (int r = 0; r < 4; r++) {                            \
        int row = qd * 4 + r;                                  \
        int rs = (row & 7) << 4;                               \
        *(__half*)(tp + row * 512 + ((wv * 64 + 2 * fr) ^ rs)) =       \
            __float2half(acc0[r] + bias0);                     \
        *(__half*)(tp + row * 512 + ((wv * 64 + 32 + 2 * fr) ^ rs)) =  \
            __float2half(acc1[r] + bias1);                     \
      }                                                        \
    }                                                          \
    if ((S) + NBLK < nstrips) stage_write((AN), tid, LC0, LC1);\
    SYNC_LDS();   /* epilogue tile + AN staging visible */     \
    {                                                          \
      int row = tid >> 5;                                      \
      int byo = (tid & 31) * 16;                               \
      float4 v = *(const float4*)((AT) + row * 512 + (byo ^ ((row & 7) << 4))); \
      *(float4*)((char*)h + (size_t)(S) * 8192 + tid * 16) = v;\
    }                                                          \
  } while (0)

__global__ __launch_bounds__(512) void gemm_mfma_kernel(
    const float* __restrict__ z, const float* __restrict__ b,
    __half* __restrict__ h, int nrows) {
  // 128KB resident B frags + 2 x 8KB A-tile double buffer = 144KB.
  __shared__ char smem[147456];
  const int tid = threadIdx.x;
  const int lane = tid & 63;
  const int wv = tid >> 6;          // 0..7 (owns cols wv*32 .. +31)
  const int fr = lane & 15;
  const int qd = lane >> 4;

  // ---- one-time B stage: linear 128KB via global_load_lds
  {
    const char* gsrc = (const char*)g_Wf;
#pragma unroll
    for (int rnd = 0; rnd < 16; rnd++) {
      int off = rnd * 8192 + wv * 1024;
      __builtin_amdgcn_global_load_lds(
          (const __attribute__((address_space(1))) void*)(gsrc + off + lane * 16),
          (__attribute__((address_space(3))) void*)(smem + off),
          16, 0, 0);
    }
  }
  const float bias0 = b[wv * 32 + fr];
  const float bias1 = b[wv * 32 + 16 + fr];

  char* atile0 = smem + 131072;
  char* atile1 = smem + 139264;
  const char* zb = (const char*)z;
  const int nstrips = (nrows + 15) >> 4;   // 6250 (exact: N%16==0)
  const half8* bw = (const half8*)smem;

  // ---- prologue: stage strip s0 into atile0 (linear, 1KB/instr)
  const int s0 = blockIdx.x;
  {
    const char* sb = zb + (size_t)s0 * 16384;
    float4 p0 = *(const float4*)(sb + tid * 16);
    float4 p1 = *(const float4*)(sb + 8192 + tid * 16);
    stage_write(atile0, tid, p0, p1);
  }
  __syncthreads();   // FULL drain once: B staging + A(s0) visible

  // depth-2 reg buffers (named; bodies alternate -> all static, rule #20)
  float4 lA0, lA1, lB0, lB1;
  if (s0 + NBLK < nstrips) {
    const char* sb = zb + (size_t)(s0 + NBLK) * 16384;
    lA0 = *(const float4*)(sb + tid * 16);
    lA1 = *(const float4*)(sb + 8192 + tid * 16);
  }

  int s = s0;
  while (true) {
    BODY(s, atile0, atile1, lA0, lA1, lB0, lB1);
    s += NBLK; if (s >= nstrips) break;
    BODY(s, atile1, atile0, lB0, lB1, lA0, lA1);
    s += NBLK; if (s >= nstrips) break;
  }
}

// 1 wave per 8 edges; per edge ONE 1KB load instr: lanes 0-31 cover the
// 512B src row, lanes 32-63 the dst row. Pair via shfl_xor(32), butterfly.
__global__ __launch_bounds__(256) void edge_dot_kernel(
    const int* __restrict__ ei, const __half* __restrict__ h,
    float* __restrict__ out, int E) {
  int wid = (blockIdx.x * blockDim.x + threadIdx.x) >> 6;
  int lane = threadIdx.x & 63;
  int ebase = wid * 8;
  if (ebase >= E) return;
  const int half = lane >> 5;      // 0=src row, 1=dst row
  const int off = lane & 31;       // float4 chunk within the 512B row

  float4 v[8];
#pragma unroll
  for (int q = 0; q < 8; q++) {
    int e = ebase + q;
    e = e < E ? e : (E - 1);
    int node = half ? ei[E + e] : ei[e];   // uniform per 32-lane half
    v[q] = *(const float4*)((const __half*)h + (size_t)node * D_DIM + off * 8);
  }

  float res = 0.f;
#pragma unroll
  for (int q = 0; q < 8; q++) {
    float4 w;
    w.x = __shfl_xor(v[q].x, 32);
    w.y = __shfl_xor(v[q].y, 32);
    w.z = __shfl_xor(v[q].z, 32);
    w.w = __shfl_xor(v[q].w, 32);
    const __half2* a2 = (const __half2*)&v[q];
    const __half2* b2 = (const __half2*)&w;
    float part = 0.f;
#pragma unroll
    for (int j = 0; j < 4; j++) {
      float2 fa = __half22float2(a2[j]);
      float2 fb = __half22float2(b2[j]);
      part += fa.x * fb.x + fa.y * fb.y;
    }
#pragma unroll
    for (int m = 1; m <= 16; m <<= 1) part += __shfl_xor(part, m);
    res = (lane == q) ? part : res;    // lanes 0..7 collect the 8 results
  }
  if (lane < 8) {
    int e = ebase + lane;
    if (e < E) out[e] = 1.0f / (1.0f + __expf(-res));
  }
}

extern "C" void kernel_launch(void* const* d_in, const int* in_sizes, int n_in,
                              void* d_out, int out_size, void* d_ws, size_t ws_size,
                              hipStream_t stream) {
  const float* z  = (const float*)d_in[0];
  const int*   ei = (const int*)d_in[1];
  const float* W  = (const float*)d_in[2];
  const float* b  = (const float*)d_in[3];
  float* out = (float*)d_out;
  __half* h  = (__half*)d_ws;   // 100000*256*2 = 51.2 MB scratch

  const int nnodes = in_sizes[0] / D_DIM;
  const int E = in_sizes[1] / 2;

  pack_w_kernel<<<32, 256, 0, stream>>>(W);

  gemm_mfma_kernel<<<NBLK, 512, 0, stream>>>(z, b, h, nnodes);

  int waves = (E + 7) / 8;                        // 1 wave per 8 edges
  dim3 grid_edge(((size_t)waves * 64 + 255) / 256);
  edge_dot_kernel<<<grid_edge, 256, 0, stream>>>(ei, h, out, E);
}

// Round 9
// 205.004 us; speedup vs baseline: 1.0072x; 1.0072x over previous
//
#include <hip/hip_runtime.h>
#include <hip/hip_bf16.h>
#include <hip/hip_fp16.h>
#include <math.h>

// Problem: h = z @ W + b  (z [N,256] fp32, W [256,256] fp32, b [256])
//          out[e] = sigmoid(dot(h[src[e]], h[dst[e]]))  for E edges
// N = 100000, E = 300000, D = 256.
//
// R21: R19 (contiguous z loads, resident-B 128KB LDS, swizzled A-tile,
// wave-private epilogue -> 202us total, gemm ~49us) + ONLY the two good
// pieces of R20 (which regressed via its rewritten epilogue):
//  (1) SYNC_LDS: s_waitcnt lgkmcnt(0) + raw s_barrier in the strip loop
//      -> global loads stay in flight ACROSS barriers; consumption is
//      ordered by register data-dependency alone (no cross-type vmcnt
//      FIFO counting -> not R15's race class).
//  (2) depth-2 strip prefetch in NAMED reg buffers (alternating body,
//      rule #20) -> stage_write waits on loads issued a full strip
//      period (~1us) earlier, not ~100cy earlier.
// Epilogue + h-stores are byte-identical to R19 (known good).
// Theory: R19's strip period (2us) = load latency exposed by the
// __syncthreads vmcnt(0) drain with 1 block/CU; BW floor is ~1us/strip.

#define D_DIM 256
#define NBLK 256

typedef __attribute__((ext_vector_type(8))) _Float16 half8;
typedef __attribute__((ext_vector_type(4))) _Float16 half4;
typedef __attribute__((ext_vector_type(4))) float f32x4;

__device__ half8 g_Wf[8 * 256 * 4];   // [kb][fn][qd][fr], 128 KB

// 8192 threads: t -> (kb, qd, n), n fastest => coalesced row reads of W.
// frag(n = fn*16+fr, qd)[j] = W[(kb*32 + qd*8 + j)*256 + n]
__global__ __launch_bounds__(256) void pack_w_kernel(const float* __restrict__ W) {
  int t = blockIdx.x * 256 + threadIdx.x;   // 0..8191
  int kb = t >> 10;
  int qd = (t >> 8) & 3;
  int n  = t & 255;
  int fn = n >> 4;
  int fr = n & 15;
  half8 o;
#pragma unroll
  for (int j = 0; j < 8; j++)
    o[j] = (_Float16)W[(size_t)(kb * 32 + qd * 8 + j) * D_DIM + n];
  g_Wf[kb * 1024 + fn * 64 + qd * 16 + fr] = o;
}

// cvt two float4 (fp32 z data) and ds_write as fp16 into swizzled A-tile.
// Thread t covers strip rows t>>6 and (t>>6)+8. Swizzle: phys = row*512
// + (inner ^ ((row&7)<<4)).
__device__ inline void stage_write(char* tile, int tid, float4 A, float4 B) {
  int row = tid >> 6;                 // 0..7
  int inner = (tid & 63) * 8;         // byte offset in 512B fp16 row
  int sw = (row & 7) << 4;
  half4 p0, p1;
  p0[0] = (_Float16)A.x; p0[1] = (_Float16)A.y;
  p0[2] = (_Float16)A.z; p0[3] = (_Float16)A.w;
  p1[0] = (_Float16)B.x; p1[1] = (_Float16)B.y;
  p1[2] = (_Float16)B.z; p1[3] = (_Float16)B.w;
  *(half4*)(tile + row * 512 + (inner ^ sw)) = p0;
  *(half4*)(tile + (row + 8) * 512 + (inner ^ sw)) = p1;
}

// LDS-only barrier: drain LDS ops, keep global loads in flight.
#define SYNC_LDS() do {                                        \
    asm volatile("" ::: "memory");                             \
    asm volatile("s_waitcnt lgkmcnt(0)" ::: "memory");         \
    __builtin_amdgcn_s_barrier();                              \
    asm volatile("" ::: "memory");                             \
  } while (0)

// One strip, R19 semantics with depth-2: issue loads(S+2N) into LN;
// MFMA from AT; SYNC; R19 epilogue into wave-private region of AT +
// 64B-chunk stores; stage A(S+N) from LC into AN; SYNC.
#define BODY(S, AT, AN, LC0, LC1, LN0, LN1) do {               \
    if ((S) + 2 * NBLK < nstrips) {                            \
      const char* sb = zb + (size_t)((S) + 2 * NBLK) * 16384;  \
      LN0 = *(const float4*)(sb + tid * 16);                   \
      LN1 = *(const float4*)(sb + 8192 + tid * 16);            \
    }                                                          \
    asm volatile("" ::: "memory");                             \
    f32x4 acc0 = (f32x4)0.f, acc1 = (f32x4)0.f;                \
    {                                                          \
      const char* abase = (AT) + fr * 512;                     \
      const int swz = (fr & 7) << 4;                           \
      _Pragma("unroll")                                        \
      for (int kb = 0; kb < 8; kb++) {                         \
        half8 af = *(const half8*)(abase + ((kb * 64 + qd * 16) ^ swz)); \
        half8 bf0 = bw[kb * 1024 + (2 * wv) * 64 + lane];      \
        half8 bf1 = bw[kb * 1024 + (2 * wv + 1) * 64 + lane];  \
        acc0 = __builtin_amdgcn_mfma_f32_16x16x32_f16(af, bf0, acc0, 0, 0, 0); \
        acc1 = __builtin_amdgcn_mfma_f32_16x16x32_f16(af, bf1, acc1, 0, 0, 0); \
      }                                                        \
    }                                                          \
    SYNC_LDS();   /* all waves done reading AT */              \
    {                                                          \
      __half* et = (__half*)((AT) + wv * 1024);                \
      _Pragma("unroll")                                        \
      for (int r = 0; r < 4; r++) {                            \
        et[(qd * 4 + r) * 32 + fr]      = __float2half(acc0[r] + bias0); \
        et[(qd * 4 + r) * 32 + 16 + fr] = __float2half(acc1[r] + bias1); \
      }                                                        \
      int row = lane >> 2, c = lane & 3;                       \
      float4 v = *(const float4*)((const char*)et + row * 64 + c * 16); \
      if ((S) + NBLK < nstrips) stage_write((AN), tid, LC0, LC1); \
      int grow = (S) * 16 + row;                               \
      if (grow < nrows)                                        \
        *(float4*)((char*)h + (size_t)grow * 512 + wv * 64 + c * 16) = v; \
    }                                                          \
    SYNC_LDS();   /* epilogue reads done; AN staging visible */\
  } while (0)

__global__ __launch_bounds__(512) void gemm_mfma_kernel(
    const float* __restrict__ z, const float* __restrict__ b,
    __half* __restrict__ h, int nrows) {
  // 128KB resident B frags + 2 x 8KB A-tile double buffer = 144KB.
  __shared__ char smem[147456];
  const int tid = threadIdx.x;
  const int lane = tid & 63;
  const int wv = tid >> 6;          // 0..7 (owns cols wv*32 .. +31)
  const int fr = lane & 15;
  const int qd = lane >> 4;

  // ---- one-time B stage: linear 128KB via global_load_lds
  {
    const char* gsrc = (const char*)g_Wf;
#pragma unroll
    for (int rnd = 0; rnd < 16; rnd++) {
      int off = rnd * 8192 + wv * 1024;
      __builtin_amdgcn_global_load_lds(
          (const __attribute__((address_space(1))) void*)(gsrc + off + lane * 16),
          (__attribute__((address_space(3))) void*)(smem + off),
          16, 0, 0);
    }
  }
  const float bias0 = b[wv * 32 + fr];
  const float bias1 = b[wv * 32 + 16 + fr];

  char* atile0 = smem + 131072;
  char* atile1 = smem + 139264;
  const char* zb = (const char*)z;
  const int nstrips = (nrows + 15) >> 4;   // 6250 (exact: N%16==0)
  const half8* bw = (const half8*)smem;

  // ---- prologue: stage strip s0 into atile0 (linear, 1KB/instr)
  const int s0 = blockIdx.x;
  {
    const char* sb = zb + (size_t)s0 * 16384;
    float4 p0 = *(const float4*)(sb + tid * 16);
    float4 p1 = *(const float4*)(sb + 8192 + tid * 16);
    stage_write(atile0, tid, p0, p1);
  }
  __syncthreads();   // FULL drain once: B staging + A(s0) visible

  // depth-2 reg buffers (named; bodies alternate -> all static, rule #20)
  float4 lA0, lA1, lB0, lB1;
  if (s0 + NBLK < nstrips) {
    const char* sb = zb + (size_t)(s0 + NBLK) * 16384;
    lA0 = *(const float4*)(sb + tid * 16);
    lA1 = *(const float4*)(sb + 8192 + tid * 16);
  }

  int s = s0;
  while (true) {
    BODY(s, atile0, atile1, lA0, lA1, lB0, lB1);
    s += NBLK; if (s >= nstrips) break;
    BODY(s, atile1, atile0, lB0, lB1, lA0, lA1);
    s += NBLK; if (s >= nstrips) break;
  }
}

// 1 wave per 8 edges; per edge ONE 1KB load instr: lanes 0-31 cover the
// 512B src row, lanes 32-63 the dst row. Pair via shfl_xor(32), butterfly.
__global__ __launch_bounds__(256) void edge_dot_kernel(
    const int* __restrict__ ei, const __half* __restrict__ h,
    float* __restrict__ out, int E) {
  int wid = (blockIdx.x * blockDim.x + threadIdx.x) >> 6;
  int lane = threadIdx.x & 63;
  int ebase = wid * 8;
  if (ebase >= E) return;
  const int half = lane >> 5;      // 0=src row, 1=dst row
  const int off = lane & 31;       // float4 chunk within the 512B row

  float4 v[8];
#pragma unroll
  for (int q = 0; q < 8; q++) {
    int e = ebase + q;
    e = e < E ? e : (E - 1);
    int node = half ? ei[E + e] : ei[e];   // uniform per 32-lane half
    v[q] = *(const float4*)((const __half*)h + (size_t)node * D_DIM + off * 8);
  }

  float res = 0.f;
#pragma unroll
  for (int q = 0; q < 8; q++) {
    float4 w;
    w.x = __shfl_xor(v[q].x, 32);
    w.y = __shfl_xor(v[q].y, 32);
    w.z = __shfl_xor(v[q].z, 32);
    w.w = __shfl_xor(v[q].w, 32);
    const __half2* a2 = (const __half2*)&v[q];
    const __half2* b2 = (const __half2*)&w;
    float part = 0.f;
#pragma unroll
    for (int j = 0; j < 4; j++) {
      float2 fa = __half22float2(a2[j]);
      float2 fb = __half22float2(b2[j]);
      part += fa.x * fb.x + fa.y * fb.y;
    }
#pragma unroll
    for (int m = 1; m <= 16; m <<= 1) part += __shfl_xor(part, m);
    res = (lane == q) ? part : res;    // lanes 0..7 collect the 8 results
  }
  if (lane < 8) {
    int e = ebase + lane;
    if (e < E) out[e] = 1.0f / (1.0f + __expf(-res));
  }
}

extern "C" void kernel_launch(void* const* d_in, const int* in_sizes, int n_in,
                              void* d_out, int out_size, void* d_ws, size_t ws_size,
                              hipStream_t stream) {
  const float* z  = (const float*)d_in[0];
  const int*   ei = (const int*)d_in[1];
  const float* W  = (const float*)d_in[2];
  const float* b  = (const float*)d_in[3];
  float* out = (float*)d_out;
  __half* h  = (__half*)d_ws;   // 100000*256*2 = 51.2 MB scratch

  const int nnodes = in_sizes[0] / D_DIM;
  const int E = in_sizes[1] / 2;

  pack_w_kernel<<<32, 256, 0, stream>>>(W);

  gemm_mfma_kernel<<<NBLK, 512, 0, stream>>>(z, b, h, nnodes);

  int waves = (E + 7) / 8;                        // 1 wave per 8 edges
  dim3 grid_edge(((size_t)waves * 64 + 255) / 256);
  edge_dot_kernel<<<grid_edge, 256, 0, stream>>>(ei, h, out, E);
}

// Round 10
// 204.521 us; speedup vs baseline: 1.0095x; 1.0024x over previous
//
#include <hip/hip_runtime.h>
#include <hip/hip_bf16.h>
#include <hip/hip_fp16.h>
#include <math.h>

// Problem: h = z @ W + b  (z [N,256] fp32, W [256,256] fp32, b [256])
//          out[e] = sigmoid(dot(h[src[e]], h[dst[e]]))  for E edges
// N = 100000, E = 300000, D = 256.
//
// R22: B-in-registers. Costing R19/R21's 2us strip period found LDS
// re-read bandwidth as the dominant serial term: 192 KB of ds_read per
// strip per CU (af 8KB + bf 16KB per wave x 8 waves) ~= 0.94us at the
// measured 85 B/cy -- half the period, invariant under all scheduling
// fixes (which is why 6 scheduling theories were null). Fix: each
// wave's B slice (2 fn cols x 8 kb = 16 half8) is exactly 64 VGPR ->
// hold B in registers PERMANENTLY (MFMA takes A and B from VGPR).
// bf LDS traffic -> 0; LDS 144KB -> 16KB (A dbuf only) -> 2 blocks/CU
// (launch_bounds(512,2), VGPR ~115); per-strip LDS 192->64KB. B init =
// 16 coalesced 1KB L2 reads/wave, once. Grid 512 persistent blocks.
// Depth-2 prefetch + LDS-only barriers kept from R21; epilogue and
// h-stores byte-identical to R19 (known good). Edge kernel untouched.

#define D_DIM 256
#define NBLK 512

typedef __attribute__((ext_vector_type(8))) _Float16 half8;
typedef __attribute__((ext_vector_type(4))) _Float16 half4;
typedef __attribute__((ext_vector_type(4))) float f32x4;

__device__ half8 g_Wf[8 * 256 * 4];   // [kb][fn][qd][fr], 128 KB

// 8192 threads: t -> (kb, qd, n), n fastest => coalesced row reads of W.
// frag(n = fn*16+fr, qd)[j] = W[(kb*32 + qd*8 + j)*256 + n]
__global__ __launch_bounds__(256) void pack_w_kernel(const float* __restrict__ W) {
  int t = blockIdx.x * 256 + threadIdx.x;   // 0..8191
  int kb = t >> 10;
  int qd = (t >> 8) & 3;
  int n  = t & 255;
  int fn = n >> 4;
  int fr = n & 15;
  half8 o;
#pragma unroll
  for (int j = 0; j < 8; j++)
    o[j] = (_Float16)W[(size_t)(kb * 32 + qd * 8 + j) * D_DIM + n];
  g_Wf[kb * 1024 + fn * 64 + qd * 16 + fr] = o;
}

// cvt two float4 (fp32 z data) and ds_write as fp16 into swizzled A-tile.
// Thread t covers strip rows t>>6 and (t>>6)+8. Swizzle: phys = row*512
// + (inner ^ ((row&7)<<4)).
__device__ inline void stage_write(char* tile, int tid, float4 A, float4 B) {
  int row = tid >> 6;                 // 0..7
  int inner = (tid & 63) * 8;         // byte offset in 512B fp16 row
  int sw = (row & 7) << 4;
  half4 p0, p1;
  p0[0] = (_Float16)A.x; p0[1] = (_Float16)A.y;
  p0[2] = (_Float16)A.z; p0[3] = (_Float16)A.w;
  p1[0] = (_Float16)B.x; p1[1] = (_Float16)B.y;
  p1[2] = (_Float16)B.z; p1[3] = (_Float16)B.w;
  *(half4*)(tile + row * 512 + (inner ^ sw)) = p0;
  *(half4*)(tile + (row + 8) * 512 + (inner ^ sw)) = p1;
}

// LDS-only barrier: drain LDS ops, keep global loads in flight.
#define SYNC_LDS() do {                                        \
    asm volatile("" ::: "memory");                             \
    asm volatile("s_waitcnt lgkmcnt(0)" ::: "memory");         \
    __builtin_amdgcn_s_barrier();                              \
    asm volatile("" ::: "memory");                             \
  } while (0)

// One strip: issue loads(S+2N) into LN; MFMA (af from AT LDS, B from
// regs); SYNC; R19 epilogue into wave-private region of AT + 64B-chunk
// stores; stage A(S+N) from LC into AN; SYNC.
#define BODY(S, AT, AN, LC0, LC1, LN0, LN1) do {               \
    if ((S) + 2 * NBLK < nstrips) {                            \
      const char* sb = zb + (size_t)((S) + 2 * NBLK) * 16384;  \
      LN0 = *(const float4*)(sb + tid * 16);                   \
      LN1 = *(const float4*)(sb + 8192 + tid * 16);            \
    }                                                          \
    asm volatile("" ::: "memory");                             \
    f32x4 acc0 = (f32x4)0.f, acc1 = (f32x4)0.f;                \
    {                                                          \
      const char* abase = (AT) + fr * 512;                     \
      const int swz = (fr & 7) << 4;                           \
      _Pragma("unroll")                                        \
      for (int kb = 0; kb < 8; kb++) {                         \
        half8 af = *(const half8*)(abase + ((kb * 64 + qd * 16) ^ swz)); \
        acc0 = __builtin_amdgcn_mfma_f32_16x16x32_f16(af, breg[kb][0], acc0, 0, 0, 0); \
        acc1 = __builtin_amdgcn_mfma_f32_16x16x32_f16(af, breg[kb][1], acc1, 0, 0, 0); \
      }                                                        \
    }                                                          \
    SYNC_LDS();   /* all waves done reading AT */              \
    {                                                          \
      __half* et = (__half*)((AT) + wv * 1024);                \
      _Pragma("unroll")                                        \
      for (int r = 0; r < 4; r++) {                            \
        et[(qd * 4 + r) * 32 + fr]      = __float2half(acc0[r] + bias0); \
        et[(qd * 4 + r) * 32 + 16 + fr] = __float2half(acc1[r] + bias1); \
      }                                                        \
      int row = lane >> 2, c = lane & 3;                       \
      float4 v = *(const float4*)((const char*)et + row * 64 + c * 16); \
      if ((S) + NBLK < nstrips) stage_write((AN), tid, LC0, LC1); \
      int grow = (S) * 16 + row;                               \
      if (grow < nrows)                                        \
        *(float4*)((char*)h + (size_t)grow * 512 + wv * 64 + c * 16) = v; \
    }                                                          \
    SYNC_LDS();   /* epilogue reads done; AN staging visible */\
  } while (0)

__global__ __launch_bounds__(512, 2) void gemm_mfma_kernel(
    const float* __restrict__ z, const float* __restrict__ b,
    __half* __restrict__ h, int nrows) {
  // A-tile double buffer only: 2 x 8KB. (B lives in registers.)
  __shared__ char smem[16384];
  const int tid = threadIdx.x;
  const int lane = tid & 63;
  const int wv = tid >> 6;          // 0..7 (owns cols wv*32 .. +31)
  const int fr = lane & 15;
  const int qd = lane >> 4;

  // ---- B slice -> registers, PERMANENT: 16 half8 = 64 VGPR.
  // Each read is a coalesced 1KB wave read from L2-resident g_Wf.
  half8 breg[8][2];
#pragma unroll
  for (int kb = 0; kb < 8; kb++)
#pragma unroll
    for (int f = 0; f < 2; f++)
      breg[kb][f] = g_Wf[kb * 1024 + (2 * wv + f) * 64 + lane];

  const float bias0 = b[wv * 32 + fr];
  const float bias1 = b[wv * 32 + 16 + fr];

  char* atile0 = smem;
  char* atile1 = smem + 8192;
  const char* zb = (const char*)z;
  const int nstrips = (nrows + 15) >> 4;   // 6250 (exact: N%16==0)

  // ---- prologue: stage strip s0 into atile0 (linear, 1KB/instr)
  const int s0 = blockIdx.x;
  if (s0 < nstrips) {
    const char* sb = zb + (size_t)s0 * 16384;
    float4 p0 = *(const float4*)(sb + tid * 16);
    float4 p1 = *(const float4*)(sb + 8192 + tid * 16);
    stage_write(atile0, tid, p0, p1);
  }
  __syncthreads();   // A(s0) staged & visible (B is per-wave regs)

  if (s0 >= nstrips) return;

  // depth-2 reg buffers (named; bodies alternate -> all static, rule #20)
  float4 lA0, lA1, lB0, lB1;
  if (s0 + NBLK < nstrips) {
    const char* sb = zb + (size_t)(s0 + NBLK) * 16384;
    lA0 = *(const float4*)(sb + tid * 16);
    lA1 = *(const float4*)(sb + 8192 + tid * 16);
  }

  int s = s0;
  while (true) {
    BODY(s, atile0, atile1, lA0, lA1, lB0, lB1);
    s += NBLK; if (s >= nstrips) break;
    BODY(s, atile1, atile0, lB0, lB1, lA0, lA1);
    s += NBLK; if (s >= nstrips) break;
  }
}

// 1 wave per 8 edges; per edge ONE 1KB load instr: lanes 0-31 cover the
// 512B src row, lanes 32-63 the dst row. Pair via shfl_xor(32), butterfly.
__global__ __launch_bounds__(256) void edge_dot_kernel(
    const int* __restrict__ ei, const __half* __restrict__ h,
    float* __restrict__ out, int E) {
  int wid = (blockIdx.x * blockDim.x + threadIdx.x) >> 6;
  int lane = threadIdx.x & 63;
  int ebase = wid * 8;
  if (ebase >= E) return;
  const int half = lane >> 5;      // 0=src row, 1=dst row
  const int off = lane & 31;       // float4 chunk within the 512B row

  float4 v[8];
#pragma unroll
  for (int q = 0; q < 8; q++) {
    int e = ebase + q;
    e = e < E ? e : (E - 1);
    int node = half ? ei[E + e] : ei[e];   // uniform per 32-lane half
    v[q] = *(const float4*)((const __half*)h + (size_t)node * D_DIM + off * 8);
  }

  float res = 0.f;
#pragma unroll
  for (int q = 0; q < 8; q++) {
    float4 w;
    w.x = __shfl_xor(v[q].x, 32);
    w.y = __shfl_xor(v[q].y, 32);
    w.z = __shfl_xor(v[q].z, 32);
    w.w = __shfl_xor(v[q].w, 32);
    const __half2* a2 = (const __half2*)&v[q];
    const __half2* b2 = (const __half2*)&w;
    float part = 0.f;
#pragma unroll
    for (int j = 0; j < 4; j++) {
      float2 fa = __half22float2(a2[j]);
      float2 fb = __half22float2(b2[j]);
      part += fa.x * fb.x + fa.y * fb.y;
    }
#pragma unroll
    for (int m = 1; m <= 16; m <<= 1) part += __shfl_xor(part, m);
    res = (lane == q) ? part : res;    // lanes 0..7 collect the 8 results
  }
  if (lane < 8) {
    int e = ebase + lane;
    if (e < E) out[e] = 1.0f / (1.0f + __expf(-res));
  }
}

extern "C" void kernel_launch(void* const* d_in, const int* in_sizes, int n_in,
                              void* d_out, int out_size, void* d_ws, size_t ws_size,
                              hipStream_t stream) {
  const float* z  = (const float*)d_in[0];
  const int*   ei = (const int*)d_in[1];
  const float* W  = (const float*)d_in[2];
  const float* b  = (const float*)d_in[3];
  float* out = (float*)d_out;
  __half* h  = (__half*)d_ws;   // 100000*256*2 = 51.2 MB scratch

  const int nnodes = in_sizes[0] / D_DIM;
  const int E = in_sizes[1] / 2;

  pack_w_kernel<<<32, 256, 0, stream>>>(W);

  gemm_mfma_kernel<<<NBLK, 512, 0, stream>>>(z, b, h, nnodes);

  int waves = (E + 7) / 8;                        // 1 wave per 8 edges
  dim3 grid_edge(((size_t)waves * 64 + 255) / 256);
  edge_dot_kernel<<<grid_edge, 256, 0, stream>>>(ei, h, out, E);
}